// Round 10
// baseline (370.437 us; speedup 1.0000x reference)
//
#include <hip/hip_runtime.h>
#include <stdint.h>

// CIN forward, MI355X. R10 = R8 skeleton, re-partitioned to halve build VALU:
// waves = batch(2) x d-half(2) x o-quad(2). Each wave: T=2 d-tiles, OT=4
// o-tiles -> one B-frag build (1 perm + 4 pkmul, quarter-rate pk ~8cyc) serves
// 4 MFMAs (was 2). Walls/SIMD: VALU 184k->92k cyc, MFMA 178.8k (16x16x32,
// 8 chains). Keeps R8-proven: scalar W addressing, depth-2 consume-then-reload
// rotation, sched_barrier(0), hv b64 parity prefetch. d-halves combine via
// sOut partials (R9-proven). 512 thr, 2 batches/block, grid 512.

typedef __attribute__((ext_vector_type(8))) _Float16 f16x8;
typedef __attribute__((ext_vector_type(2))) _Float16 f16x2;
typedef __attribute__((ext_vector_type(4))) float f32x4;
typedef __attribute__((ext_vector_type(4))) int i32x4;

static __device__ __forceinline__ uint32_t pkmul(uint32_t a, uint32_t b) {
  f16x2 r = __builtin_bit_cast(f16x2, a) * __builtin_bit_cast(f16x2, b);
  return __builtin_bit_cast(uint32_t, r);  // v_pk_mul_f16
}
static __device__ __forceinline__ uint32_t pkcvt(float a, float b) {
  return __builtin_bit_cast(uint32_t, __builtin_amdgcn_cvt_pkrtz(a, b));
}
static __device__ __forceinline__ f16x8 asf16(i32x4 v) {
  return __builtin_bit_cast(f16x8, v);
}

#define HP 136  // hT row: 128 ch + 8 pad (tail hv prefetch lands in pad)

__global__ __launch_bounds__(512, 4) void cin_main(
    const float* __restrict__ x, const uint16_t* __restrict__ wp,
    const float* __restrict__ bias0, const float* __restrict__ bias1,
    const float* __restrict__ bias2, float* __restrict__ out) {
  __shared__ __align__(16) uint16_t hT[2][64][HP];  // [batch][d][chan] fp16
  __shared__ float sOut[2][2][128];                 // [batch][dhalf][o]

  const int tid = threadIdx.x;
  const int w = tid >> 6, lane = tid & 63;
  const int p  = __builtin_amdgcn_readfirstlane(w >> 2);       // batch
  const int th = __builtin_amdgcn_readfirstlane((w >> 1) & 1); // d-half: t=2th+t2
  const int og = __builtin_amdgcn_readfirstlane(w & 1);        // o-quad: ot=4og+g
  const int q = lane >> 4;   // k-quad: B row k = q*8+j; C row o = q*4+r
  const int i = lane & 15;   // d within tile (B/C col); A row o (mod 16)
  const int bb = blockIdx.x * 2;

  // ---- stage x -> hT[p][d][m] fp16 (layer-0 h == x; 32 channels)
  for (int e = tid; e < 4096; e += 512) {
    int p2 = e >> 11, m = (e >> 6) & 31, d = e & 63;
    hT[p2][d][m] =
        __builtin_bit_cast(uint16_t, (_Float16)x[(size_t)(bb + p2) * 2048 + m * 64 + d]);
  }
  __syncthreads();

  // ---- x B-frags (loop-invariant): xf[t2].j = x[m=q*8+j][d=(2th+t2)*16+i]
  i32x4 xf[2];
#pragma unroll
  for (int t2 = 0; t2 < 2; ++t2)
    xf[t2] = *(const i32x4*)&hT[p][(2 * th + t2) * 16 + i][q * 8];  // ds_read_b128

  f32x4 acc[2][4];           // [t2][g] : 8 independent chains
  const int loff = lane * 8; // the only vector address component

#pragma unroll
  for (int L = 0; L < 3; ++L) {
    const int Kch = (L == 0) ? 32 : 128;
    const uint16_t* wl = (L == 0) ? wp : (L == 1) ? wp + 131072 : wp + 655360;
    const float* bias = (L == 0) ? bias0 : (L == 1) ? bias1 : bias2;

    // uniform (SGPR) W bases; frag(ot,c) at (ot*Kch + c)*512 elems
    const uint16_t* wb0 = wl + (size_t)(4 * og + 0) * Kch * 512;
    const uint16_t* wb1 = wl + (size_t)(4 * og + 1) * Kch * 512;
    const uint16_t* wb2 = wl + (size_t)(4 * og + 2) * Kch * 512;
    const uint16_t* wb3 = wl + (size_t)(4 * og + 3) * Kch * 512;

#pragma unroll
    for (int t2 = 0; t2 < 2; ++t2)
#pragma unroll
      for (int g = 0; g < 4; ++g) acc[t2][g] = (f32x4){0.f, 0.f, 0.f, 0.f};

    i32x4 wbuf[2][2][4];  // [slot][cc][g]: 64 VGPR, depth-2 rotation
    uint2 hvA[2], hvB[2];
    const uint16_t* hrow0 = &hT[p][(2 * th + 0) * 16 + i][0];
    const uint16_t* hrow1 = &hT[p][(2 * th + 1) * 16 + i][0];

    auto loadSlot = [&](int s, int co) {  // 2 channels x 4 o-tiles
#pragma unroll
      for (int cc = 0; cc < 2; ++cc) {
        wbuf[s][cc][0] = *(const i32x4*)(wb0 + co + cc * 512 + loff);
        wbuf[s][cc][1] = *(const i32x4*)(wb1 + co + cc * 512 + loff);
        wbuf[s][cc][2] = *(const i32x4*)(wb2 + co + cc * 512 + loff);
        wbuf[s][cc][3] = *(const i32x4*)(wb3 + co + cc * 512 + loff);
      }
    };
    auto loadHv = [&](uint2 (&hv)[2]) {  // 4 channels per t2 row (ds_read_b64)
      hv[0] = *(const uint2*)hrow0; hrow0 += 4;
      hv[1] = *(const uint2*)hrow1; hrow1 += 4;
    };
    // one channel-pair: w0/w1 hold (ch c, ch c+1) f16 pairs for t2=0/1 rows
    auto computePair = [&](int s, uint32_t w0, uint32_t w1) {
#pragma unroll
      for (int cc = 0; cc < 2; ++cc) {
        const uint32_t sel = cc ? 0x03020302u : 0x01000100u;
#pragma unroll
        for (int t2 = 0; t2 < 2; ++t2) {
          uint32_t word = t2 ? w1 : w0;
          uint32_t hd = __builtin_amdgcn_perm(word, word, sel);  // dup h[c,d]
          i32x4 bf;  // P[c*32 + q*8+j][d] = h[c,d]*x[q*8+j,d]
#pragma unroll
          for (int k = 0; k < 4; ++k) bf[k] = (int)pkmul(hd, (uint32_t)xf[t2][k]);
#pragma unroll
          for (int g = 0; g < 4; ++g)
            acc[t2][g] = __builtin_amdgcn_mfma_f32_16x16x32_f16(
                asf16(wbuf[s][cc][g]), asf16(bf), acc[t2][g], 0, 0, 0);
        }
      }
    };

    // prologue: slot0 = ch{0,1}, slot1 = ch{2,3}; co -> ch4; hvA = ch0..3
    loadSlot(0, 0);
    loadSlot(1, 1024);
    int co = 2048;
    const int comax = (Kch - 4) * 512;
    loadHv(hvA);
    __builtin_amdgcn_sched_barrier(0);

#pragma unroll 1
    for (int c0 = 0; c0 < Kch; c0 += 8) {
      // body 1: ch c0..c0+3 via hvA
      loadHv(hvB);
      computePair(0, hvA[0].x, hvA[1].x);   // consume, THEN reload
      loadSlot(0, co);
      __builtin_amdgcn_sched_barrier(0);
      computePair(1, hvA[0].y, hvA[1].y);
      loadSlot(1, co + 1024);
      __builtin_amdgcn_sched_barrier(0);
      co = (co + 2048 < comax) ? co + 2048 : comax;  // scalar clamp
      // body 2: ch c0+4..c0+7 via hvB
      loadHv(hvA);  // tail prefetch lands in row pad (in-bounds, unused)
      computePair(0, hvB[0].x, hvB[1].x);
      loadSlot(0, co);
      __builtin_amdgcn_sched_barrier(0);
      computePair(1, hvB[0].y, hvB[1].y);
      loadSlot(1, co + 1024);
      __builtin_amdgcn_sched_barrier(0);
      co = (co + 2048 < comax) ? co + 2048 : comax;
    }

    // ---- bias + ReLU (C layout: o = (4og+g)*16 + q*4 + r, d = (2th+t2)*16 + i)
#pragma unroll
    for (int g = 0; g < 4; ++g) {
      f32x4 bv = *(const f32x4*)(bias + (4 * og + g) * 16 + q * 4);
#pragma unroll
      for (int t2 = 0; t2 < 2; ++t2)
#pragma unroll
        for (int r = 0; r < 4; ++r)
          acc[t2][g][r] = fmaxf(acc[t2][g][r] + bv[r], 0.f);
    }

    __syncthreads();  // all hT reads of this layer done

    if (L < 2) {  // next-layer h -> hT (disjoint row/col ranges per wave)
#pragma unroll
      for (int t2 = 0; t2 < 2; ++t2)
#pragma unroll
        for (int g = 0; g < 4; ++g) {
          uint2 pk;
          pk.x = pkcvt(acc[t2][g][0], acc[t2][g][1]);
          pk.y = pkcvt(acc[t2][g][2], acc[t2][g][3]);
          *(uint2*)&hT[p][(2 * th + t2) * 16 + i][(4 * og + g) * 16 + q * 4] = pk;
        }
    }

    // d-partials over this wave's 32 d (2 t2 in-register + 16 i-lanes shuffle)
#pragma unroll
    for (int g = 0; g < 4; ++g)
#pragma unroll
      for (int r = 0; r < 4; ++r) {
        float s = acc[0][g][r] + acc[1][g][r];
        s += __shfl_xor(s, 1);
        s += __shfl_xor(s, 2);
        s += __shfl_xor(s, 4);
        s += __shfl_xor(s, 8);
        if (i == 0) sOut[p][th][(4 * og + g) * 16 + q * 4 + r] = s;
      }

    __syncthreads();  // sOut partials + hT writes visible

    // combine d-halves -> out (coalesced; 256 lanes = 2 batches x 128 o)
    if (tid < 256) {
      int b2 = tid >> 7, o = tid & 127;
      out[(size_t)(bb + b2) * 384 + L * 128 + o] = sOut[b2][0][o] + sOut[b2][1][o];
    }
    // next sOut write is after the next layer's K-loop -> single buffer safe
  }
}

// One pack kernel for all 3 layers (R7/R8-verified). Reads coalesced along k;
// writes fp16 frags: dst elem (ot*Kch+c)*512 + q*128 + i*8; content
// A[m=lane&15][k=(lane>>4)*8+j] = W[ot*16+m][c*32+k].
__global__ void pack_w_all(const float* __restrict__ W0, const float* __restrict__ W1,
                           const float* __restrict__ W2, uint16_t* __restrict__ Wp) {
  int blk = blockIdx.x;
  const float* W;
  uint16_t* dst;
  int kshift;
  if (blk < 64)       { W = W0; dst = Wp;          kshift = 5; }
  else if (blk < 320) { W = W1; dst = Wp + 131072; kshift = 7; blk -= 64; }
  else                { W = W2; dst = Wp + 655360; kshift = 7; blk -= 320; }
  int idx = blk * 256 + threadIdx.x;
  int Kq = 1 << (kshift + 2);        // Kch*4 = K/8
  int o = idx >> (kshift + 2);
  int kq = idx & (Kq - 1);
  int c = kq >> 2, q = kq & 3;
  int ot = o >> 4, ii = o & 15;
  const float* src = W + ((size_t)o << (kshift + 5)) + kq * 8;
  uint4 val;
  val.x = pkcvt(src[0], src[1]);
  val.y = pkcvt(src[2], src[3]);
  val.z = pkcvt(src[4], src[5]);
  val.w = pkcvt(src[6], src[7]);
  *(uint4*)(dst + ((((size_t)ot << kshift) + c) << 9) + (q << 7) + (ii << 3)) = val;
}

extern "C" void kernel_launch(void* const* d_in, const int* in_sizes, int n_in,
                              void* d_out, int out_size, void* d_ws, size_t ws_size,
                              hipStream_t stream) {
  (void)in_sizes; (void)n_in; (void)out_size; (void)ws_size;
  const float* x  = (const float*)d_in[0];
  const float* W0 = (const float*)d_in[1];
  const float* b0 = (const float*)d_in[2];
  const float* W1 = (const float*)d_in[3];
  const float* b1 = (const float*)d_in[4];
  const float* W2 = (const float*)d_in[5];
  const float* b2 = (const float*)d_in[6];
  uint16_t* wpacked = (uint16_t*)d_ws;  // 2.25 MB of ws

  hipLaunchKernelGGL(pack_w_all, dim3(576), dim3(256), 0, stream, W0, W1, W2, wpacked);
  hipLaunchKernelGGL(cin_main, dim3(512), dim3(512), 0, stream,
                     x, wpacked, b0, b1, b2, (float*)d_out);
}

// Round 11
// 229.855 us; speedup vs baseline: 1.6116x; 1.6116x over previous
//
#include <hip/hip_runtime.h>
#include <stdint.h>

// CIN forward, MI355X. R11 = R10's partition with the spill fixed.
// R10 spilled (WRITE_SIZE 340MB): compiler targeted 8 waves/EU (LDS allows
// 4 blocks/CU) and capped arch VGPRs at 64 < wbuf's 64. Grid caps occupancy
// at 4 waves/SIMD anyway -> amdgpu_waves_per_eu(4,4) unlocks 128 VGPRs, and
// slots shrink to 1 channel (16 VGPRs each, depth-2 = 32: R8/R9-proven size).
// Waves = batch(2) x d-half(2) x o-quad(2): one B-frag build (1 perm +
// 4 pkmul, quarter-rate) serves 4 MFMAs. 16x16x32 f16, 8 acc chains.
// Scalar rolling W offset, consume-then-reload, sched_barrier(0), hv b64
// parity prefetch, sOut d-half combine. 512 thr, 2 batches/block, grid 512.

typedef __attribute__((ext_vector_type(8))) _Float16 f16x8;
typedef __attribute__((ext_vector_type(2))) _Float16 f16x2;
typedef __attribute__((ext_vector_type(4))) float f32x4;
typedef __attribute__((ext_vector_type(4))) int i32x4;

static __device__ __forceinline__ uint32_t pkmul(uint32_t a, uint32_t b) {
  f16x2 r = __builtin_bit_cast(f16x2, a) * __builtin_bit_cast(f16x2, b);
  return __builtin_bit_cast(uint32_t, r);  // v_pk_mul_f16
}
static __device__ __forceinline__ uint32_t pkcvt(float a, float b) {
  return __builtin_bit_cast(uint32_t, __builtin_amdgcn_cvt_pkrtz(a, b));
}
static __device__ __forceinline__ f16x8 asf16(i32x4 v) {
  return __builtin_bit_cast(f16x8, v);
}

#define HP 136  // hT row: 128 ch + 8 pad (tail hv prefetch lands in pad)

__global__ __launch_bounds__(512) __attribute__((amdgpu_waves_per_eu(4, 4)))
void cin_main(
    const float* __restrict__ x, const uint16_t* __restrict__ wp,
    const float* __restrict__ bias0, const float* __restrict__ bias1,
    const float* __restrict__ bias2, float* __restrict__ out) {
  __shared__ __align__(16) uint16_t hT[2][64][HP];  // [batch][d][chan] fp16
  __shared__ float sOut[2][2][128];                 // [batch][dhalf][o]

  const int tid = threadIdx.x;
  const int w = tid >> 6, lane = tid & 63;
  const int p  = __builtin_amdgcn_readfirstlane(w >> 2);       // batch
  const int th = __builtin_amdgcn_readfirstlane((w >> 1) & 1); // d-half: t=2th+t2
  const int og = __builtin_amdgcn_readfirstlane(w & 1);        // o-quad: ot=4og+g
  const int q = lane >> 4;   // k-quad: B row k = q*8+j; C row o = q*4+r
  const int i = lane & 15;   // d within tile (B/C col); A row o (mod 16)
  const int bb = blockIdx.x * 2;

  // ---- stage x -> hT[p][d][m] fp16 (layer-0 h == x; 32 channels)
  for (int e = tid; e < 4096; e += 512) {
    int p2 = e >> 11, m = (e >> 6) & 31, d = e & 63;
    hT[p2][d][m] =
        __builtin_bit_cast(uint16_t, (_Float16)x[(size_t)(bb + p2) * 2048 + m * 64 + d]);
  }
  __syncthreads();

  // ---- x B-frags (loop-invariant): xf[t2].j = x[m=q*8+j][d=(2th+t2)*16+i]
  i32x4 xf[2];
#pragma unroll
  for (int t2 = 0; t2 < 2; ++t2)
    xf[t2] = *(const i32x4*)&hT[p][(2 * th + t2) * 16 + i][q * 8];  // ds_read_b128

  f32x4 acc[2][4];           // [t2][g] : 8 independent chains
  const int loff = lane * 8; // the only vector address component

#pragma unroll
  for (int L = 0; L < 3; ++L) {
    const int Kch = (L == 0) ? 32 : 128;
    const uint16_t* wl = (L == 0) ? wp : (L == 1) ? wp + 131072 : wp + 655360;
    const float* bias = (L == 0) ? bias0 : (L == 1) ? bias1 : bias2;

    // uniform (SGPR) W bases; frag(ot,c) at (ot*Kch + c)*512 elems
    const uint16_t* wb0 = wl + (size_t)(4 * og + 0) * Kch * 512;
    const uint16_t* wb1 = wl + (size_t)(4 * og + 1) * Kch * 512;
    const uint16_t* wb2 = wl + (size_t)(4 * og + 2) * Kch * 512;
    const uint16_t* wb3 = wl + (size_t)(4 * og + 3) * Kch * 512;

#pragma unroll
    for (int t2 = 0; t2 < 2; ++t2)
#pragma unroll
      for (int g = 0; g < 4; ++g) acc[t2][g] = (f32x4){0.f, 0.f, 0.f, 0.f};

    i32x4 slotA[4], slotB[4];  // 1 channel x 4 o-tiles each: 16 VGPRs/slot
    uint2 hvA[2], hvB[2];
    const uint16_t* hrow0 = &hT[p][(2 * th + 0) * 16 + i][0];
    const uint16_t* hrow1 = &hT[p][(2 * th + 1) * 16 + i][0];

    auto loadSlot = [&](i32x4 (&sl)[4], int co) {  // one channel, 4 o-tiles
      sl[0] = *(const i32x4*)(wb0 + co + loff);
      sl[1] = *(const i32x4*)(wb1 + co + loff);
      sl[2] = *(const i32x4*)(wb2 + co + loff);
      sl[3] = *(const i32x4*)(wb3 + co + loff);
    };
    auto loadHv = [&](uint2 (&hv)[2]) {  // 4 channels per t2 row (ds_read_b64)
      hv[0] = *(const uint2*)hrow0; hrow0 += 4;
      hv[1] = *(const uint2*)hrow1; hrow1 += 4;
    };
    // one channel: w0/w1 = dwords holding this ch pair for rows t2=0/1
    auto compCh = [&](const i32x4 (&sl)[4], uint32_t w0, uint32_t w1,
                      uint32_t sel) {
#pragma unroll
      for (int t2 = 0; t2 < 2; ++t2) {
        uint32_t word = t2 ? w1 : w0;
        uint32_t hd = __builtin_amdgcn_perm(word, word, sel);  // dup h[c,d]
        i32x4 bf;  // P[c*32 + q*8+j][d] = h[c,d]*x[q*8+j,d]
#pragma unroll
        for (int k = 0; k < 4; ++k) bf[k] = (int)pkmul(hd, (uint32_t)xf[t2][k]);
#pragma unroll
        for (int g = 0; g < 4; ++g)
          acc[t2][g] = __builtin_amdgcn_mfma_f32_16x16x32_f16(
              asf16(sl[g]), asf16(bf), acc[t2][g], 0, 0, 0);
      }
    };

    // prologue: slotA=ch0, slotB=ch1; co -> ch2; hvA = ch0..3
    loadSlot(slotA, 0);
    loadSlot(slotB, 512);
    int co = 1024;
    const int comax = (Kch - 1) * 512;
    loadHv(hvA);
    __builtin_amdgcn_sched_barrier(0);

    // 4-channel body: consume hvC, prefetch hvN; slot invariant
    // {slotA,slotB} = {c, c+1} at entry of each channel step.
    auto body4 = [&](const uint2 (&hvC)[2], uint2 (&hvN)[2]) {
      loadHv(hvN);  // tail prefetch lands in row pad (in-bounds, unused)
      compCh(slotA, hvC[0].x, hvC[1].x, 0x01000100u);  // ch c
      loadSlot(slotA, co);                              // -> ch c+2
      __builtin_amdgcn_sched_barrier(0);
      co = (co + 512 < comax) ? co + 512 : comax;
      compCh(slotB, hvC[0].x, hvC[1].x, 0x03020302u);  // ch c+1
      loadSlot(slotB, co);                              // -> ch c+3
      __builtin_amdgcn_sched_barrier(0);
      co = (co + 512 < comax) ? co + 512 : comax;
      compCh(slotA, hvC[0].y, hvC[1].y, 0x01000100u);  // ch c+2
      loadSlot(slotA, co);
      __builtin_amdgcn_sched_barrier(0);
      co = (co + 512 < comax) ? co + 512 : comax;
      compCh(slotB, hvC[0].y, hvC[1].y, 0x03020302u);  // ch c+3
      loadSlot(slotB, co);
      __builtin_amdgcn_sched_barrier(0);
      co = (co + 512 < comax) ? co + 512 : comax;
    };

#pragma unroll 1
    for (int c0 = 0; c0 < Kch; c0 += 8) {
      body4(hvA, hvB);
      body4(hvB, hvA);
    }

    // ---- bias + ReLU (C layout: o = (4og+g)*16 + q*4 + r, d = (2th+t2)*16 + i)
#pragma unroll
    for (int g = 0; g < 4; ++g) {
      f32x4 bv = *(const f32x4*)(bias + (4 * og + g) * 16 + q * 4);
#pragma unroll
      for (int t2 = 0; t2 < 2; ++t2)
#pragma unroll
        for (int r = 0; r < 4; ++r)
          acc[t2][g][r] = fmaxf(acc[t2][g][r] + bv[r], 0.f);
    }

    __syncthreads();  // all hT reads of this layer done

    if (L < 2) {  // next-layer h -> hT (disjoint row/col ranges per wave)
#pragma unroll
      for (int t2 = 0; t2 < 2; ++t2)
#pragma unroll
        for (int g = 0; g < 4; ++g) {
          uint2 pk;
          pk.x = pkcvt(acc[t2][g][0], acc[t2][g][1]);
          pk.y = pkcvt(acc[t2][g][2], acc[t2][g][3]);
          *(uint2*)&hT[p][(2 * th + t2) * 16 + i][(4 * og + g) * 16 + q * 4] = pk;
        }
    }

    // d-partials over this wave's 32 d (2 t2 in-register + 16 i-lanes shuffle)
#pragma unroll
    for (int g = 0; g < 4; ++g)
#pragma unroll
      for (int r = 0; r < 4; ++r) {
        float s = acc[0][g][r] + acc[1][g][r];
        s += __shfl_xor(s, 1);
        s += __shfl_xor(s, 2);
        s += __shfl_xor(s, 4);
        s += __shfl_xor(s, 8);
        if (i == 0) sOut[p][th][(4 * og + g) * 16 + q * 4 + r] = s;
      }

    __syncthreads();  // sOut partials + hT writes visible

    // combine d-halves -> out (coalesced; 256 lanes = 2 batches x 128 o)
    if (tid < 256) {
      int b2 = tid >> 7, o = tid & 127;
      out[(size_t)(bb + b2) * 384 + L * 128 + o] = sOut[b2][0][o] + sOut[b2][1][o];
    }
    // next sOut write is after the next layer's K-loop -> single buffer safe
  }
}

// One pack kernel for all 3 layers (R7/R8-verified). Reads coalesced along k;
// writes fp16 frags: dst elem (ot*Kch+c)*512 + q*128 + i*8; content
// A[m=lane&15][k=(lane>>4)*8+j] = W[ot*16+m][c*32+k].
__global__ void pack_w_all(const float* __restrict__ W0, const float* __restrict__ W1,
                           const float* __restrict__ W2, uint16_t* __restrict__ Wp) {
  int blk = blockIdx.x;
  const float* W;
  uint16_t* dst;
  int kshift;
  if (blk < 64)       { W = W0; dst = Wp;          kshift = 5; }
  else if (blk < 320) { W = W1; dst = Wp + 131072; kshift = 7; blk -= 64; }
  else                { W = W2; dst = Wp + 655360; kshift = 7; blk -= 320; }
  int idx = blk * 256 + threadIdx.x;
  int Kq = 1 << (kshift + 2);        // Kch*4 = K/8
  int o = idx >> (kshift + 2);
  int kq = idx & (Kq - 1);
  int c = kq >> 2, q = kq & 3;
  int ot = o >> 4, ii = o & 15;
  const float* src = W + ((size_t)o << (kshift + 5)) + kq * 8;
  uint4 val;
  val.x = pkcvt(src[0], src[1]);
  val.y = pkcvt(src[2], src[3]);
  val.z = pkcvt(src[4], src[5]);
  val.w = pkcvt(src[6], src[7]);
  *(uint4*)(dst + ((((size_t)ot << kshift) + c) << 9) + (q << 7) + (ii << 3)) = val;
}

extern "C" void kernel_launch(void* const* d_in, const int* in_sizes, int n_in,
                              void* d_out, int out_size, void* d_ws, size_t ws_size,
                              hipStream_t stream) {
  (void)in_sizes; (void)n_in; (void)out_size; (void)ws_size;
  const float* x  = (const float*)d_in[0];
  const float* W0 = (const float*)d_in[1];
  const float* b0 = (const float*)d_in[2];
  const float* W1 = (const float*)d_in[3];
  const float* b1 = (const float*)d_in[4];
  const float* W2 = (const float*)d_in[5];
  const float* b2 = (const float*)d_in[6];
  uint16_t* wpacked = (uint16_t*)d_ws;  // 2.25 MB of ws

  hipLaunchKernelGGL(pack_w_all, dim3(576), dim3(256), 0, stream, W0, W1, W2, wpacked);
  hipLaunchKernelGGL(cin_main, dim3(512), dim3(512), 0, stream,
                     x, wpacked, b0, b1, b2, (float*)d_out);
}